// Round 6
// baseline (146.228 us; speedup 1.0000x reference)
//
#include <hip/hip_runtime.h>

#define NB    16
#define CIN   16
#define COUT  32
#define DIN   32
#define DOUT  30

typedef __attribute__((ext_vector_type(8)))  short        short8;
typedef __attribute__((ext_vector_type(4)))  unsigned int uint4v;
typedef __attribute__((ext_vector_type(16))) float        f32x16;

// ws layout (bytes):
//   [0      .. 55296)      : W A-fragments, bf16 hi then lo (27*64*16 * 2)
//   [57344  .. 57344+32MB) : x as bf16 hi/lo chunks (repack_x), if ws_size permits
#define XWS_OFS_SHORTS   28672        // 57344 B
#define XWS_PART_SHORTS  8388608      // 16 MB per part (hi, lo)
#define WS_NEED          (57344 + 2ull * 16 * 1024 * 1024)

static __device__ __forceinline__ unsigned short f2bf_rne(float f) {
    unsigned int u = __builtin_bit_cast(unsigned int, f);
    u += 0x7fffu + ((u >> 16) & 1u);
    return (unsigned short)(u >> 16);
}
static __device__ __forceinline__ float bf2f(unsigned short s) {
    unsigned int u = ((unsigned int)s) << 16;
    return __builtin_bit_cast(float, u);
}
// packed f32x2 -> bf16x2 (RNE), src0 -> low half
static __device__ __forceinline__ unsigned int cvt_pk_bf16(float a, float b) {
    unsigned int r;
    asm("v_cvt_pk_bf16_f32 %0, %1, %2" : "=v"(r) : "v"(a), "v"(b));
    return r;
}
// async global->LDS, 16B per lane; lds dst = uniform base + lane*16
static __device__ __forceinline__ void gload_lds16(const short* g, short* l) {
    __builtin_amdgcn_global_load_lds(
        (const __attribute__((address_space(1))) void*)g,
        (__attribute__((address_space(3))) void*)l, 16, 0, 0);
}

// Kernel 1: repack W[Cout][Cin][3][3][3] fp32 into MFMA A-fragment layout, bf16 hi/lo split.
__global__ __launch_bounds__(64) void repack_w(const float* __restrict__ wgt,
                                               short* __restrict__ ws) {
    const int s  = blockIdx.x;    // 0..26  (kd*9+kh*3+kw)
    const int l  = threadIdx.x;   // 0..63
    const int co  = l & 31;
    const int ci0 = (l >> 5) * 8;
    short8 vh, vl;
#pragma unroll
    for (int j = 0; j < 8; ++j) {
        float f = wgt[co * (CIN * 27) + (ci0 + j) * 27 + s];
        unsigned short h = f2bf_rne(f);
        vh[j] = (short)h;
        vl[j] = (short)f2bf_rne(f - bf2f(h));
    }
    ((short8*)ws)[s * 64 + l]            = vh;
    ((short8*)ws)[27 * 64 + s * 64 + l]  = vl;
}

// Kernel 1b: repack x[b][ci][d][h][w] fp32 -> bf16 hi/lo chunks.
// Per row-plane rp=(b*32+d)*32+h: 64 chunks (hi8*32+w), each 8 ci x bf16 = 16B.
__global__ __launch_bounds__(256) void repack_x(const float* __restrict__ x,
                                                short* __restrict__ xws) {
    const int rp  = blockIdx.x * 4 + (threadIdx.x >> 6);   // 0..16383
    const int l   = threadIdx.x & 63;
    const int hi8 = l >> 5, w = l & 31;
    const int b   = rp >> 10;
    const int dh  = rp & 1023;                              // d*32+h
    const int gbase = b * (CIN * 32768) + hi8 * 8 * 32768 + dh * 32 + w;
    float f[8];
#pragma unroll
    for (int j = 0; j < 8; ++j) f[j] = x[gbase + j * 32768];
    uint4v vh, vl;
#pragma unroll
    for (int j = 0; j < 8; j += 2) {
        unsigned int hp = cvt_pk_bf16(f[j], f[j + 1]);
        float b0 = __builtin_bit_cast(float, hp << 16);
        float b1 = __builtin_bit_cast(float, hp & 0xffff0000u);
        unsigned int lp = cvt_pk_bf16(f[j] - b0, f[j + 1] - b1);
        vh[j >> 1] = hp;
        vl[j >> 1] = lp;
    }
    ((uint4v*)xws)[rp * 64 + l]               = vh;
    ((uint4v*)xws)[1048576 + rp * 64 + l]     = vl;
}

// Main kernel v5: d-quad per WAVE. Block (htile, dblk, b) = 4 waves (256 thr).
// Wave wy computes output rows (b, :, d0+t, h0+wy, :) for t=0..3 (4 accumulator tiles).
// LDS: 6 planes x 6 rows, hi/lo = 72 KB -> 2 blocks/CU. Per e=(kh,kw): 6 A-loads +
// 12 B ds_reads feed 36 MFMAs (t-chains independent). A depth-1 prefetch across e.
__global__ __launch_bounds__(256, 2) void conv3d_mfma_v5(
    const short* __restrict__ xws,
    const short* __restrict__ wsA,
    const float* __restrict__ cbias,
    const float* __restrict__ scal,
    const float* __restrict__ bpar,
    float* __restrict__ out)
{
    __shared__ __align__(16) short sx[2 * 18432];   // hi at 0, lo at +18432 shorts (72 KB)
    __shared__ float sp[96];

    const int htile = blockIdx.x;   // 0..7
    const int dblk  = blockIdx.y;   // 0..7
    const int b     = blockIdx.z;   // 0..15

    const int tid  = threadIdx.x;
    const int ww   = tid >> 6;      // 0..3 = wy
    const int lane = tid & 63;

    if (tid < 32) {
        sp[tid]      = cbias[tid];
        sp[32 + tid] = scal[tid];
        sp[64 + tid] = bpar[tid];
    }

    const int h0 = htile * 4;
    const int d0 = dblk * 4;

    // ---- stage 36 row-planes (6 planes x 6 rows), hi+lo, async global_load_lds ----
#pragma unroll
    for (int t = 0; t < 9; ++t) {
        const int rpl = ww + t * 4;               // 0..35 = dz*6+row, exact coverage
        const int dz  = rpl / 6;
        const int row = rpl - dz * 6;
        int d_in = d0 + dz; if (d_in > 31) d_in = 31;   // dblk 7 halo clamp (feeds only unstored tiles)
        int h_in = h0 + row; if (h_in > 31) h_in = 31;  // htile 7 halo clamp (rows unused by valid waves)
        const int grp = (b * 32 + d_in) * 32 + h_in;
        gload_lds16(xws + (size_t)grp * 512 + lane * 8, sx + rpl * 512);
        gload_lds16(xws + XWS_PART_SHORTS + (size_t)grp * 512 + lane * 8,
                    sx + 18432 + rpl * 512);
    }
    __syncthreads();   // drains vmcnt(0) before barrier

    const int wy = ww;
    const int h  = h0 + wy;
    if (h >= DOUT) return;    // only barrier above; safe to exit (htile 7, wy 2/3)

    const int n  = lane & 31;   // output w (30 valid + 2 pad)
    const int hi = lane >> 5;

    // per-kw LDS base pointers (shorts); dz/kh/lo fold into immediate offsets
    const short* pb[3];
#pragma unroll
    for (int kw = 0; kw < 3; ++kw) {
        int wc = n + kw; if (wc > 31) wc = 31;   // pad lanes clamp (cols >=30 discarded)
        pb[kw] = sx + wy * 512 + hi * 256 + wc * 8;
    }

    f32x16 acc0, acc1, acc2, acc3;
#pragma unroll
    for (int i = 0; i < 16; ++i) { acc0[i] = 0.0f; acc1[i] = 0.0f; acc2[i] = 0.0f; acc3[i] = 0.0f; }

    const short8* wa = (const short8*)wsA;

    // A double-buffer: preload e=0 (slices kd*9+e, kd=0..2)
    short8 Ah0 = wa[0 * 64 + lane],  Ah1 = wa[9 * 64 + lane],  Ah2 = wa[18 * 64 + lane];
    short8 Al0 = wa[1728 + 0 * 64 + lane], Al1 = wa[1728 + 9 * 64 + lane],
           Al2 = wa[1728 + 18 * 64 + lane];

#pragma unroll
    for (int e = 0; e < 9; ++e) {
        const int kh = e / 3, kw = e - kh * 3;
        const int en = (e < 8) ? e + 1 : 8;
        // prefetch next-e A fragments (hidden under this e's 36 MFMAs)
        short8 Anh0 = wa[(0 * 9 + en) * 64 + lane];
        short8 Anh1 = wa[(1 * 9 + en) * 64 + lane];
        short8 Anh2 = wa[(2 * 9 + en) * 64 + lane];
        short8 Anl0 = wa[1728 + (0 * 9 + en) * 64 + lane];
        short8 Anl1 = wa[1728 + (1 * 9 + en) * 64 + lane];
        short8 Anl2 = wa[1728 + (2 * 9 + en) * 64 + lane];

        const short* base = pb[kw] + kh * 512;
#pragma unroll
        for (int dz = 0; dz < 6; ++dz) {
            const short8 bh = *(const short8*)(base + dz * 3072);
            const short8 bl = *(const short8*)(base + 18432 + dz * 3072);
            __builtin_amdgcn_s_setprio(1);
            // tile t (output d0+t) uses kd = dz - t in [0,2]
#pragma unroll
            for (int t = 0; t < 4; ++t) {
                const int kd = dz - t;
                if (kd >= 0 && kd <= 2) {
                    const short8 ah = (kd == 0) ? Ah0 : (kd == 1) ? Ah1 : Ah2;
                    const short8 al = (kd == 0) ? Al0 : (kd == 1) ? Al1 : Al2;
                    if (t == 0) {
                        acc0 = __builtin_amdgcn_mfma_f32_32x32x16_bf16(ah, bh, acc0, 0, 0, 0);
                        acc0 = __builtin_amdgcn_mfma_f32_32x32x16_bf16(ah, bl, acc0, 0, 0, 0);
                        acc0 = __builtin_amdgcn_mfma_f32_32x32x16_bf16(al, bh, acc0, 0, 0, 0);
                    } else if (t == 1) {
                        acc1 = __builtin_amdgcn_mfma_f32_32x32x16_bf16(ah, bh, acc1, 0, 0, 0);
                        acc1 = __builtin_amdgcn_mfma_f32_32x32x16_bf16(ah, bl, acc1, 0, 0, 0);
                        acc1 = __builtin_amdgcn_mfma_f32_32x32x16_bf16(al, bh, acc1, 0, 0, 0);
                    } else if (t == 2) {
                        acc2 = __builtin_amdgcn_mfma_f32_32x32x16_bf16(ah, bh, acc2, 0, 0, 0);
                        acc2 = __builtin_amdgcn_mfma_f32_32x32x16_bf16(ah, bl, acc2, 0, 0, 0);
                        acc2 = __builtin_amdgcn_mfma_f32_32x32x16_bf16(al, bh, acc2, 0, 0, 0);
                    } else {
                        acc3 = __builtin_amdgcn_mfma_f32_32x32x16_bf16(ah, bh, acc3, 0, 0, 0);
                        acc3 = __builtin_amdgcn_mfma_f32_32x32x16_bf16(ah, bl, acc3, 0, 0, 0);
                        acc3 = __builtin_amdgcn_mfma_f32_32x32x16_bf16(al, bh, acc3, 0, 0, 0);
                    }
                }
            }
            __builtin_amdgcn_s_setprio(0);
        }
        Ah0 = Anh0; Ah1 = Anh1; Ah2 = Anh2;
        Al0 = Anl0; Al1 = Anl1; Al2 = Anl2;
    }

    // ---- epilogue: bias, tanh*scale, *bp, sigmoid; C/D map: co=(r&3)+8*(r>>2)+4*hi ----
    if (n < DOUT) {
        const int obase = b * (COUT * DOUT * DOUT * DOUT) + d0 * (DOUT * DOUT) + h * DOUT + n;
#pragma unroll
        for (int r = 0; r < 16; ++r) {
            const int co = (r & 3) + 8 * (r >> 2) + 4 * hi;
            const float cb = sp[co], sc = sp[32 + co], bp = sp[64 + co];
            const int ob = obase + co * (DOUT * DOUT * DOUT);
#pragma unroll
            for (int t = 0; t < 4; ++t) {
                if (d0 + t < DOUT) {
                    const float a = (t == 0) ? acc0[r] : (t == 1) ? acc1[r]
                                  : (t == 2) ? acc2[r] : acc3[r];
                    float y  = a + cb;
                    float tt = y * sc;
                    float th = 1.0f - 2.0f / (__expf(2.0f * tt) + 1.0f);
                    float z  = th * bp;
                    out[ob + t * (DOUT * DOUT)] = 1.0f / (1.0f + __expf(-z));
                }
            }
        }
    }
}

// Fallback (ws too small): v1, in-kernel conversion staging (passing baseline).
__global__ __launch_bounds__(512) void conv3d_mfma_v1(
    const float* __restrict__ x,
    const short* __restrict__ wsA,
    const float* __restrict__ cbias,
    const float* __restrict__ scal,
    const float* __restrict__ bpar,
    float* __restrict__ out)
{
    __shared__ __align__(16) short sx[2 * 12288];
    __shared__ float sp[96];

    const int htile = blockIdx.x;
    const int dpair = blockIdx.y;
    const int b     = blockIdx.z;

    const int tid  = threadIdx.x;
    const int ww   = tid >> 6;
    const int wd   = ww >> 2;
    const int wy   = ww & 3;
    const int lane = tid & 63;

    if (tid < 32) {
        sp[tid]      = cbias[tid];
        sp[32 + tid] = scal[tid];
        sp[64 + tid] = bpar[tid];
    }

    const int h0 = htile * 4;
    const int d0 = dpair * 2;

    const int xb = b * (CIN * DIN * DIN * DIN);
    for (int c = tid; c < 1536; c += 512) {
        const int w   = c & 31;
        const int hi8 = (c >> 5) & 1;
        const int rr  = c >> 6;
        const int dz  = rr / 6;
        const int row = rr - dz * 6;
        int h_in = h0 + row; if (h_in > 31) h_in = 31;
        const int gbase = xb + (hi8 * 8) * (DIN * DIN * DIN)
                        + (d0 + dz) * (DIN * DIN) + h_in * DIN + w;
        float f[8];
#pragma unroll
        for (int j = 0; j < 8; ++j) f[j] = x[gbase + j * (DIN * DIN * DIN)];
        uint4v vh, vl;
#pragma unroll
        for (int j = 0; j < 8; j += 2) {
            unsigned int hp = cvt_pk_bf16(f[j], f[j + 1]);
            float b0 = __builtin_bit_cast(float, hp << 16);
            float b1 = __builtin_bit_cast(float, hp & 0xffff0000u);
            unsigned int lp = cvt_pk_bf16(f[j] - b0, f[j + 1] - b1);
            vh[j >> 1] = hp;
            vl[j >> 1] = lp;
        }
        const int idx = rr * 64 + hi8 * 32 + w;
        *(uint4v*)(sx + idx * 8)         = vh;
        *(uint4v*)(sx + 12288 + idx * 8) = vl;
    }
    __syncthreads();

    const int h = h0 + wy;
    if (h >= DOUT) return;
    const int d = d0 + wd;

    const int n  = lane & 31;
    const int hi = lane >> 5;

    int wofs[3];
#pragma unroll
    for (int kw = 0; kw < 3; ++kw) {
        int wc = n + kw; if (wc > 31) wc = 31;
        wofs[kw] = hi * 256 + wc * 8;
    }

    f32x16 acc;
#pragma unroll
    for (int i = 0; i < 16; ++i) acc[i] = 0.0f;

    const short8* wa = (const short8*)wsA;
#pragma unroll
    for (int kd = 0; kd < 3; ++kd) {
#pragma unroll
        for (int kh = 0; kh < 3; ++kh) {
            const int rbase = ((wd + kd) * 6 + wy + kh) * 512;
#pragma unroll
            for (int kw = 0; kw < 3; ++kw) {
                const int s = kd * 9 + kh * 3 + kw;
                short8 ah = wa[s * 64 + lane];
                short8 al = wa[1728 + s * 64 + lane];
                short8 bh = *(const short8*)(sx + rbase + wofs[kw]);
                short8 bl = *(const short8*)(sx + 12288 + rbase + wofs[kw]);
                acc = __builtin_amdgcn_mfma_f32_32x32x16_bf16(ah, bh, acc, 0, 0, 0);
                acc = __builtin_amdgcn_mfma_f32_32x32x16_bf16(ah, bl, acc, 0, 0, 0);
                acc = __builtin_amdgcn_mfma_f32_32x32x16_bf16(al, bh, acc, 0, 0, 0);
            }
        }
    }

    if (n < DOUT) {
        const int obase = b * (COUT * DOUT * DOUT * DOUT)
                        + d * (DOUT * DOUT) + h * DOUT + n;
#pragma unroll
        for (int r = 0; r < 16; ++r) {
            const int co = (r & 3) + 8 * (r >> 2) + 4 * hi;
            float y  = acc[r] + sp[co];
            float t  = y * sp[32 + co];
            float th = 1.0f - 2.0f / (__expf(2.0f * t) + 1.0f);
            float z  = th * sp[64 + co];
            float rr = 1.0f / (1.0f + __expf(-z));
            out[obase + co * (DOUT * DOUT * DOUT)] = rr;
        }
    }
}

extern "C" void kernel_launch(void* const* d_in, const int* in_sizes, int n_in,
                              void* d_out, int out_size, void* d_ws, size_t ws_size,
                              hipStream_t stream) {
    const float* x     = (const float*)d_in[0];
    const float* wgt   = (const float*)d_in[1];
    const float* cbias = (const float*)d_in[2];
    const float* scal  = (const float*)d_in[3];
    const float* bpar  = (const float*)d_in[4];
    float* out = (float*)d_out;
    short* ws  = (short*)d_ws;

    hipLaunchKernelGGL(repack_w, dim3(27), dim3(64), 0, stream, wgt, ws);

    if (ws_size >= WS_NEED) {
        short* xws = ws + XWS_OFS_SHORTS;
        hipLaunchKernelGGL(repack_x, dim3(4096), dim3(256), 0, stream, x, xws);
        hipLaunchKernelGGL(conv3d_mfma_v5, dim3(8, 8, NB), dim3(256), 0, stream,
                           xws, ws, cbias, scal, bpar, out);
    } else {
        hipLaunchKernelGGL(conv3d_mfma_v1, dim3(8, 15, NB), dim3(512), 0, stream,
                           x, ws, cbias, scal, bpar, out);
    }
}